// Round 1
// baseline (3552.281 us; speedup 1.0000x reference)
//
#include <hip/hip_runtime.h>

#define NN 50000
#define NE 800000

__global__ void deg_init(float* deg, int n) {
    int i = blockIdx.x * blockDim.x + threadIdx.x;
    if (i < n) deg[i] = 1.0f;  // self-loop
}

__global__ void deg_acc(const int* __restrict__ dst, float* deg, int e) {
    int i = blockIdx.x * blockDim.x + threadIdx.x;
    if (i < e) atomicAdd(deg + dst[i], 1.0f);
}

__global__ void dinv_k(float* deg, int n) {
    int i = blockIdx.x * blockDim.x + threadIdx.x;
    if (i < n) deg[i] = rsqrtf(deg[i]);  // deg >= 1 always (self-loop)
}

// G[i][j] = dinv[i] * sum_k X[i][k] * W[k][j];  OUT initialized to G (self-loop term)
template<int K>
__global__ void gemm_scale(const float* __restrict__ X, const float* __restrict__ W,
                           const float* __restrict__ dinv,
                           float* __restrict__ G, float* __restrict__ OUT, int n) {
    __shared__ float Xs[32 * 128];
    int row0 = blockIdx.x * 32;
    int tid = threadIdx.x;
    const float4* Xv = (const float4*)(X + (size_t)row0 * 128);
    float4* Xsv = (float4*)Xs;
#pragma unroll
    for (int i = 0; i < 4; i++) {
        int idx = tid + i * 256;          // float4 index in tile (1024 total)
        int r = idx >> 5;                 // 32 float4 per row
        if (row0 + r < n) Xsv[idx] = Xv[idx];
        else Xsv[idx] = make_float4(0.f, 0.f, 0.f, 0.f);
    }
    __syncthreads();
    for (int o = tid; o < 32 * K; o += 256) {
        int r = o / K, j = o - r * K;
        int row = row0 + r;
        if (row >= n) break;              // r nondecreasing in o
        float acc = 0.f;
        const float* xs = Xs + r * 128;
#pragma unroll
        for (int k = 0; k < 128; k++) acc = fmaf(xs[k], W[k * K + j], acc);
        float g = dinv[row] * acc;
        size_t off = (size_t)row * K + j;
        G[off] = g;
        OUT[off] = g;
    }
}

template<int K>
__global__ void scatter_add(const float* __restrict__ G, float* __restrict__ OUT,
                            const int* __restrict__ src, const int* __restrict__ dst) {
    long long t = (long long)blockIdx.x * blockDim.x + threadIdx.x;
    if (t >= (long long)NE * K) return;
    int e = (int)(t / K);
    int f = (int)(t - (long long)e * K);
    int s = src[e], d = dst[e];
    atomicAdd(OUT + (size_t)d * K + f, G[(size_t)s * K + f]);
}

template<int K>
__global__ void finalize_relu(const float* __restrict__ OUT, const float* __restrict__ dinv,
                              const float* __restrict__ b, float* __restrict__ Y, int n) {
    long long t = (long long)blockIdx.x * blockDim.x + threadIdx.x;
    if (t >= (long long)n * K) return;
    int i = (int)(t / K);
    int j = (int)(t - (long long)i * K);
    float v = fmaf(dinv[i], OUT[t], b[j]);
    Y[t] = v > 0.f ? v : 0.f;
}

// one 64-lane wave per row of 40 classes: scale+bias, then log_softmax
__global__ void finalize_lsm(const float* __restrict__ OUT, const float* __restrict__ dinv,
                             const float* __restrict__ b, float* __restrict__ Y, int n) {
    int gid = blockIdx.x * blockDim.x + threadIdx.x;
    int row = gid >> 6;
    int lane = threadIdx.x & 63;
    if (row >= n) return;
    float v = -1e30f;
    if (lane < 40) v = fmaf(dinv[row], OUT[(size_t)row * 40 + lane], b[lane]);
    float m = v;
#pragma unroll
    for (int off = 32; off > 0; off >>= 1) m = fmaxf(m, __shfl_xor(m, off, 64));
    float ex = (lane < 40) ? expf(v - m) : 0.f;
    float s = ex;
#pragma unroll
    for (int off = 32; off > 0; off >>= 1) s += __shfl_xor(s, off, 64);
    float ls = logf(s);
    if (lane < 40) Y[(size_t)row * 40 + lane] = v - m - ls;
}

extern "C" void kernel_launch(void* const* d_in, const int* in_sizes, int n_in,
                              void* d_out, int out_size, void* d_ws, size_t ws_size,
                              hipStream_t stream) {
    const float* x  = (const float*)d_in[0];
    const int*   ei = (const int*)d_in[1];
    const float* W1 = (const float*)d_in[2];
    const float* b1 = (const float*)d_in[3];
    const float* W2 = (const float*)d_in[4];
    const float* b2 = (const float*)d_in[5];
    const float* W3 = (const float*)d_in[6];
    const float* b3 = (const float*)d_in[7];
    float* out = (float*)d_out;

    const int n = NN, e = NE;
    const int* srcI = ei;        // edge_index[0]
    const int* dstI = ei + e;    // edge_index[1]

    char* ws = (char*)d_ws;
    float* dinv = (float*)ws;                      // N floats (also deg scratch)
    float* bufA = (float*)(ws + 200704);           // N*128
    float* bufG = bufA + (size_t)n * 128;          // N*128
    float* bufO = bufG + (size_t)n * 128;          // N*128

    // degree -> dinv
    deg_init<<<(n + 255) / 256, 256, 0, stream>>>(dinv, n);
    deg_acc<<<(e + 255) / 256, 256, 0, stream>>>(dstI, dinv, e);
    dinv_k<<<(n + 255) / 256, 256, 0, stream>>>(dinv, n);

    unsigned gs128 = (unsigned)(((long long)e * 128 + 255) / 256);
    unsigned gf128 = (unsigned)(((long long)n * 128 + 255) / 256);
    unsigned gs40  = (unsigned)(((long long)e * 40 + 255) / 256);

    // layer 1: 128 -> 128, relu
    gemm_scale<128><<<(n + 31) / 32, 256, 0, stream>>>(x, W1, dinv, bufG, bufO, n);
    scatter_add<128><<<gs128, 256, 0, stream>>>(bufG, bufO, srcI, dstI);
    finalize_relu<128><<<gf128, 256, 0, stream>>>(bufO, dinv, b1, bufA, n);

    // layer 2: 128 -> 128, relu
    gemm_scale<128><<<(n + 31) / 32, 256, 0, stream>>>(bufA, W2, dinv, bufG, bufO, n);
    scatter_add<128><<<gs128, 256, 0, stream>>>(bufG, bufO, srcI, dstI);
    finalize_relu<128><<<gf128, 256, 0, stream>>>(bufO, dinv, b2, bufA, n);

    // layer 3: 128 -> 40, log_softmax
    gemm_scale<40><<<(n + 31) / 32, 256, 0, stream>>>(bufA, W3, dinv, bufG, bufO, n);
    scatter_add<40><<<gs40, 256, 0, stream>>>(bufG, bufO, srcI, dstI);
    finalize_lsm<<<(n + 3) / 4, 256, 0, stream>>>(bufO, dinv, b3, out, n);
}

// Round 3
// 1071.220 us; speedup vs baseline: 3.3161x; 3.3161x over previous
//
#include <hip/hip_runtime.h>

#define NN 50000
#define NE 800000

// XOR-swizzle for WsT[j][k] stored at stride 128: xor touches bits 2..4 of k
// only (k%4==0 on reads), keeping float4 reads contiguous while spreading
// tx-lanes across bank groups.
#define SWZ(j, k) ((j) * 128 + ((k) ^ (((j) & 7) << 2)))

__global__ void deg_init(float* deg, int n) {
    int i = blockIdx.x * blockDim.x + threadIdx.x;
    if (i < n) deg[i] = 1.0f;  // self-loop
}

__global__ void deg_acc(const int* __restrict__ dst, float* deg, int e) {
    int i = blockIdx.x * blockDim.x + threadIdx.x;
    if (i < e) atomicAdd(deg + dst[i], 1.0f);
}

__global__ void dinv_k(float* deg, int n) {
    int i = blockIdx.x * blockDim.x + threadIdx.x;
    if (i < n) deg[i] = rsqrtf(deg[i]);  // deg >= 1 always
}

// G[i][j] = dinv[i] * sum_k X[i][k] * W[k][j]; dual store to G and OUT (self-loop init).
// 256 threads, 128 rows x 128 cols per block, 8x8 register tile per thread.
__global__ __launch_bounds__(256) void gemm128(const float* __restrict__ X,
                                               const float* __restrict__ W,
                                               const float* __restrict__ dinv,
                                               float* __restrict__ G,
                                               float* __restrict__ OUT, int n) {
    __shared__ float WsT[128 * 128];  // 64 KB
    int t = threadIdx.x;
    int row0 = blockIdx.x * 128;

    // stage W transposed: W[k][j] -> WsT[j*128 + (k ^ ((j&7)<<2))]
    const float4* Wv = (const float4*)W;
#pragma unroll
    for (int i = 0; i < 16; i++) {
        int idx = t + i * 256;            // 0..4095 float4s
        int k = idx >> 5;                 // 32 float4 per W row
        int j4 = (idx & 31) * 4;
        float4 v = Wv[idx];
        WsT[(j4 + 0) * 128 + (k ^ (((j4 + 0) & 7) << 2))] = v.x;
        WsT[(j4 + 1) * 128 + (k ^ (((j4 + 1) & 7) << 2))] = v.y;
        WsT[(j4 + 2) * 128 + (k ^ (((j4 + 2) & 7) << 2))] = v.z;
        WsT[(j4 + 3) * 128 + (k ^ (((j4 + 3) & 7) << 2))] = v.w;
    }
    __syncthreads();

    int tx = t & 15;   // cols = tx + 16*ci
    int ty = t >> 4;   // rows = ty + 16*ri

    const float* xp[8];
#pragma unroll
    for (int ri = 0; ri < 8; ri++) {
        int row = row0 + ty + 16 * ri;
        int rowc = row < n ? row : n - 1;        // clamp; store is guarded
        xp[ri] = X + (size_t)rowc * 128;
    }

    float acc[8][8];
#pragma unroll
    for (int ri = 0; ri < 8; ri++)
#pragma unroll
        for (int ci = 0; ci < 8; ci++) acc[ri][ci] = 0.f;

#pragma unroll 2
    for (int k = 0; k < 128; k += 4) {
        float4 a[8], b[8];
#pragma unroll
        for (int ri = 0; ri < 8; ri++) a[ri] = *(const float4*)(xp[ri] + k);
#pragma unroll
        for (int ci = 0; ci < 8; ci++) {
            int col = tx + 16 * ci;
            b[ci] = *(const float4*)(&WsT[SWZ(col, k)]);
        }
#pragma unroll
        for (int ri = 0; ri < 8; ri++)
#pragma unroll
            for (int ci = 0; ci < 8; ci++) {
                acc[ri][ci] = fmaf(a[ri].x, b[ci].x, acc[ri][ci]);
                acc[ri][ci] = fmaf(a[ri].y, b[ci].y, acc[ri][ci]);
                acc[ri][ci] = fmaf(a[ri].z, b[ci].z, acc[ri][ci]);
                acc[ri][ci] = fmaf(a[ri].w, b[ci].w, acc[ri][ci]);
            }
    }

#pragma unroll
    for (int ri = 0; ri < 8; ri++) {
        int row = row0 + ty + 16 * ri;
        if (row >= n) continue;
        float di = dinv[row];
#pragma unroll
        for (int ci = 0; ci < 8; ci++) {
            int col = tx + 16 * ci;
            float g = di * acc[ri][ci];
            size_t off = (size_t)row * 128 + col;
            G[off] = g;
            OUT[off] = g;
        }
    }
}

// K=40 variant: 128 rows/block, 4x5 register tile, WsT 40x128 (20 KB) in LDS.
__global__ __launch_bounds__(256) void gemm40(const float* __restrict__ X,
                                              const float* __restrict__ W,
                                              const float* __restrict__ dinv,
                                              float* __restrict__ G,
                                              float* __restrict__ OUT, int n) {
    __shared__ float WsT[40 * 128];  // 20 KB
    int t = threadIdx.x;
    int row0 = blockIdx.x * 128;

    const float4* Wv = (const float4*)W;  // W: 128x40 -> 1280 float4s
#pragma unroll
    for (int i = 0; i < 5; i++) {
        int idx = t + i * 256;  // 0..1279
        int k = idx / 10;       // 10 float4 per W row
        int j4 = (idx - k * 10) * 4;
        float4 v = Wv[idx];
        WsT[(j4 + 0) * 128 + (k ^ (((j4 + 0) & 7) << 2))] = v.x;
        WsT[(j4 + 1) * 128 + (k ^ (((j4 + 1) & 7) << 2))] = v.y;
        WsT[(j4 + 2) * 128 + (k ^ (((j4 + 2) & 7) << 2))] = v.z;
        WsT[(j4 + 3) * 128 + (k ^ (((j4 + 3) & 7) << 2))] = v.w;
    }
    __syncthreads();

    int tx = t & 7;   // cols = tx*5 + ci
    int ty = t >> 3;  // rows = ty + 32*ri

    const float* xp[4];
#pragma unroll
    for (int ri = 0; ri < 4; ri++) {
        int row = row0 + ty + 32 * ri;
        int rowc = row < n ? row : n - 1;
        xp[ri] = X + (size_t)rowc * 128;
    }

    float acc[4][5];
#pragma unroll
    for (int ri = 0; ri < 4; ri++)
#pragma unroll
        for (int ci = 0; ci < 5; ci++) acc[ri][ci] = 0.f;

#pragma unroll 2
    for (int k = 0; k < 128; k += 4) {
        float4 a[4], b[5];
#pragma unroll
        for (int ri = 0; ri < 4; ri++) a[ri] = *(const float4*)(xp[ri] + k);
#pragma unroll
        for (int ci = 0; ci < 5; ci++) {
            int col = tx * 5 + ci;
            b[ci] = *(const float4*)(&WsT[SWZ(col, k)]);
        }
#pragma unroll
        for (int ri = 0; ri < 4; ri++)
#pragma unroll
            for (int ci = 0; ci < 5; ci++) {
                acc[ri][ci] = fmaf(a[ri].x, b[ci].x, acc[ri][ci]);
                acc[ri][ci] = fmaf(a[ri].y, b[ci].y, acc[ri][ci]);
                acc[ri][ci] = fmaf(a[ri].z, b[ci].z, acc[ri][ci]);
                acc[ri][ci] = fmaf(a[ri].w, b[ci].w, acc[ri][ci]);
            }
    }

#pragma unroll
    for (int ri = 0; ri < 4; ri++) {
        int row = row0 + ty + 32 * ri;
        if (row >= n) continue;
        float di = dinv[row];
#pragma unroll
        for (int ci = 0; ci < 5; ci++) {
            int col = tx * 5 + ci;
            float g = di * acc[ri][ci];
            size_t off = (size_t)row * 40 + col;
            G[off] = g;
            OUT[off] = g;
        }
    }
}

template<int K>
__global__ void scatter_add(const float* __restrict__ G, float* __restrict__ OUT,
                            const int* __restrict__ src, const int* __restrict__ dst) {
    long long t = (long long)blockIdx.x * blockDim.x + threadIdx.x;
    if (t >= (long long)NE * K) return;
    int e = (int)(t / K);
    int f = (int)(t - (long long)e * K);
    int s = src[e], d = dst[e];
    atomicAdd(OUT + (size_t)d * K + f, G[(size_t)s * K + f]);
}

template<int K>
__global__ void finalize_relu(const float* __restrict__ OUT, const float* __restrict__ dinv,
                              const float* __restrict__ b, float* __restrict__ Y, int n) {
    long long t = (long long)blockIdx.x * blockDim.x + threadIdx.x;
    if (t >= (long long)n * K) return;
    int i = (int)(t / K);
    int j = (int)(t - (long long)i * K);
    float v = fmaf(dinv[i], OUT[t], b[j]);
    Y[t] = v > 0.f ? v : 0.f;
}

// one 64-lane wave per row of 40 classes
__global__ void finalize_lsm(const float* __restrict__ OUT, const float* __restrict__ dinv,
                             const float* __restrict__ b, float* __restrict__ Y, int n) {
    int gid = blockIdx.x * blockDim.x + threadIdx.x;
    int row = gid >> 6;
    int lane = threadIdx.x & 63;
    if (row >= n) return;
    float v = -1e30f;
    if (lane < 40) v = fmaf(dinv[row], OUT[(size_t)row * 40 + lane], b[lane]);
    float m = v;
#pragma unroll
    for (int off = 32; off > 0; off >>= 1) m = fmaxf(m, __shfl_xor(m, off, 64));
    float ex = (lane < 40) ? expf(v - m) : 0.f;
    float s = ex;
#pragma unroll
    for (int off = 32; off > 0; off >>= 1) s += __shfl_xor(s, off, 64);
    float ls = logf(s);
    if (lane < 40) Y[(size_t)row * 40 + lane] = v - m - ls;
}

extern "C" void kernel_launch(void* const* d_in, const int* in_sizes, int n_in,
                              void* d_out, int out_size, void* d_ws, size_t ws_size,
                              hipStream_t stream) {
    const float* x  = (const float*)d_in[0];
    const int*   ei = (const int*)d_in[1];
    const float* W1 = (const float*)d_in[2];
    const float* b1 = (const float*)d_in[3];
    const float* W2 = (const float*)d_in[4];
    const float* b2 = (const float*)d_in[5];
    const float* W3 = (const float*)d_in[6];
    const float* b3 = (const float*)d_in[7];
    float* out = (float*)d_out;

    const int n = NN, e = NE;
    const int* srcI = ei;        // edge_index[0]
    const int* dstI = ei + e;    // edge_index[1]

    char* ws = (char*)d_ws;
    float* dinv = (float*)ws;                      // N floats
    float* bufA = (float*)(ws + 200704);           // N*128
    float* bufG = bufA + (size_t)n * 128;          // N*128
    float* bufO = bufG + (size_t)n * 128;          // N*128

    deg_init<<<(n + 255) / 256, 256, 0, stream>>>(dinv, n);
    deg_acc<<<(e + 255) / 256, 256, 0, stream>>>(dstI, dinv, e);
    dinv_k<<<(n + 255) / 256, 256, 0, stream>>>(dinv, n);

    unsigned gg = (unsigned)((n + 127) / 128);     // 391
    unsigned gs128 = (unsigned)(((long long)e * 128 + 255) / 256);
    unsigned gf128 = (unsigned)(((long long)n * 128 + 255) / 256);
    unsigned gs40  = (unsigned)(((long long)e * 40 + 255) / 256);

    // layer 1
    gemm128<<<gg, 256, 0, stream>>>(x, W1, dinv, bufG, bufO, n);
    scatter_add<128><<<gs128, 256, 0, stream>>>(bufG, bufO, srcI, dstI);
    finalize_relu<128><<<gf128, 256, 0, stream>>>(bufO, dinv, b1, bufA, n);

    // layer 2
    gemm128<<<gg, 256, 0, stream>>>(bufA, W2, dinv, bufG, bufO, n);
    scatter_add<128><<<gs128, 256, 0, stream>>>(bufG, bufO, srcI, dstI);
    finalize_relu<128><<<gf128, 256, 0, stream>>>(bufO, dinv, b2, bufA, n);

    // layer 3
    gemm40<<<gg, 256, 0, stream>>>(bufA, W3, dinv, bufG, bufO, n);
    scatter_add<40><<<gs40, 256, 0, stream>>>(bufG, bufO, srcI, dstI);
    finalize_lsm<<<(n + 3) / 4, 256, 0, stream>>>(bufO, dinv, b3, out, n);
}

// Round 4
// 534.252 us; speedup vs baseline: 6.6491x; 2.0051x over previous
//
#include <hip/hip_runtime.h>

#define NN 50000
#define NE 800000

#define SWZ(j, k) ((j) * 128 + ((k) ^ (((j) & 7) << 2)))

// ---------- CSR build ----------

__global__ void zero_i(int* p, int n) {
    int i = blockIdx.x * blockDim.x + threadIdx.x;
    if (i < n) p[i] = 0;
}

__global__ void hist_acc(const int* __restrict__ dst, int* hist, int e) {
    int i = blockIdx.x * blockDim.x + threadIdx.x;
    if (i < e) atomicAdd(hist + dst[i], 1);
}

__global__ void dinv_k(const int* __restrict__ hist, float* dinv, int n) {
    int i = blockIdx.x * blockDim.x + threadIdx.x;
    if (i < n) dinv[i] = rsqrtf(1.0f + (float)hist[i]);  // +1 self-loop
}

// inclusive scan per 256-block -> exclusive row_ptr piece + block sum
__global__ void scan1(const int* __restrict__ hist, int* row_ptr, int* bsum, int n) {
    __shared__ int s[256];
    int tid = threadIdx.x;
    int i = blockIdx.x * 256 + tid;
    int v = (i < n) ? hist[i] : 0;
    s[tid] = v;
    __syncthreads();
#pragma unroll
    for (int off = 1; off < 256; off <<= 1) {
        int y = (tid >= off) ? s[tid - off] : 0;
        __syncthreads();
        s[tid] += y;
        __syncthreads();
    }
    if (i < n) row_ptr[i] = s[tid] - v;          // exclusive within block
    if (tid == 255) bsum[blockIdx.x] = s[255];   // block total
}

// exclusive scan of block sums (nb <= 256), in place -> boff
__global__ void scan2(const int* __restrict__ bsum, int* boff, int nb) {
    __shared__ int s[256];
    int tid = threadIdx.x;
    int v = (tid < nb) ? bsum[tid] : 0;
    s[tid] = v;
    __syncthreads();
#pragma unroll
    for (int off = 1; off < 256; off <<= 1) {
        int y = (tid >= off) ? s[tid - off] : 0;
        __syncthreads();
        s[tid] += y;
        __syncthreads();
    }
    if (tid < nb) boff[tid] = s[tid] - v;
}

// add block offsets; init running position counters
__global__ void scan3(int* row_ptr, const int* __restrict__ boff, int* pos, int n) {
    int i = blockIdx.x * blockDim.x + threadIdx.x;
    if (i < n) {
        int rp = row_ptr[i] + boff[i >> 8];
        row_ptr[i] = rp;
        pos[i] = rp;
    }
}

// bucket edges by dst; after this, pos[d] = row end for node d
__global__ void bucket(const int* __restrict__ src, const int* __restrict__ dst,
                       int* pos, int* csr_src, int e) {
    int i = blockIdx.x * blockDim.x + threadIdx.x;
    if (i < e) {
        int p = atomicAdd(pos + dst[i], 1);
        csr_src[p] = src[i];
    }
}

// ---------- GEMMs (write G only) ----------

__global__ __launch_bounds__(256) void gemm128(const float* __restrict__ X,
                                               const float* __restrict__ W,
                                               const float* __restrict__ dinv,
                                               float* __restrict__ G, int n) {
    __shared__ float WsT[128 * 128];
    int t = threadIdx.x;
    int row0 = blockIdx.x * 128;

    const float4* Wv = (const float4*)W;
#pragma unroll
    for (int i = 0; i < 16; i++) {
        int idx = t + i * 256;
        int k = idx >> 5;
        int j4 = (idx & 31) * 4;
        float4 v = Wv[idx];
        WsT[(j4 + 0) * 128 + (k ^ (((j4 + 0) & 7) << 2))] = v.x;
        WsT[(j4 + 1) * 128 + (k ^ (((j4 + 1) & 7) << 2))] = v.y;
        WsT[(j4 + 2) * 128 + (k ^ (((j4 + 2) & 7) << 2))] = v.z;
        WsT[(j4 + 3) * 128 + (k ^ (((j4 + 3) & 7) << 2))] = v.w;
    }
    __syncthreads();

    int tx = t & 15;
    int ty = t >> 4;

    const float* xp[8];
#pragma unroll
    for (int ri = 0; ri < 8; ri++) {
        int row = row0 + ty + 16 * ri;
        int rowc = row < n ? row : n - 1;
        xp[ri] = X + (size_t)rowc * 128;
    }

    float acc[8][8];
#pragma unroll
    for (int ri = 0; ri < 8; ri++)
#pragma unroll
        for (int ci = 0; ci < 8; ci++) acc[ri][ci] = 0.f;

#pragma unroll 2
    for (int k = 0; k < 128; k += 4) {
        float4 a[8], b[8];
#pragma unroll
        for (int ri = 0; ri < 8; ri++) a[ri] = *(const float4*)(xp[ri] + k);
#pragma unroll
        for (int ci = 0; ci < 8; ci++) b[ci] = *(const float4*)(&WsT[SWZ(tx + 16 * ci, k)]);
#pragma unroll
        for (int ri = 0; ri < 8; ri++)
#pragma unroll
            for (int ci = 0; ci < 8; ci++) {
                acc[ri][ci] = fmaf(a[ri].x, b[ci].x, acc[ri][ci]);
                acc[ri][ci] = fmaf(a[ri].y, b[ci].y, acc[ri][ci]);
                acc[ri][ci] = fmaf(a[ri].z, b[ci].z, acc[ri][ci]);
                acc[ri][ci] = fmaf(a[ri].w, b[ci].w, acc[ri][ci]);
            }
    }

#pragma unroll
    for (int ri = 0; ri < 8; ri++) {
        int row = row0 + ty + 16 * ri;
        if (row >= n) continue;
        float di = dinv[row];
#pragma unroll
        for (int ci = 0; ci < 8; ci++)
            G[(size_t)row * 128 + tx + 16 * ci] = di * acc[ri][ci];
    }
}

__global__ __launch_bounds__(256) void gemm40(const float* __restrict__ X,
                                              const float* __restrict__ W,
                                              const float* __restrict__ dinv,
                                              float* __restrict__ G, int n) {
    __shared__ float WsT[40 * 128];
    int t = threadIdx.x;
    int row0 = blockIdx.x * 128;

    const float4* Wv = (const float4*)W;
#pragma unroll
    for (int i = 0; i < 5; i++) {
        int idx = t + i * 256;
        int k = idx / 10;
        int j4 = (idx - k * 10) * 4;
        float4 v = Wv[idx];
        WsT[(j4 + 0) * 128 + (k ^ (((j4 + 0) & 7) << 2))] = v.x;
        WsT[(j4 + 1) * 128 + (k ^ (((j4 + 1) & 7) << 2))] = v.y;
        WsT[(j4 + 2) * 128 + (k ^ (((j4 + 2) & 7) << 2))] = v.z;
        WsT[(j4 + 3) * 128 + (k ^ (((j4 + 3) & 7) << 2))] = v.w;
    }
    __syncthreads();

    int tx = t & 7;
    int ty = t >> 3;

    const float* xp[4];
#pragma unroll
    for (int ri = 0; ri < 4; ri++) {
        int row = row0 + ty + 32 * ri;
        int rowc = row < n ? row : n - 1;
        xp[ri] = X + (size_t)rowc * 128;
    }

    float acc[4][5];
#pragma unroll
    for (int ri = 0; ri < 4; ri++)
#pragma unroll
        for (int ci = 0; ci < 5; ci++) acc[ri][ci] = 0.f;

#pragma unroll 2
    for (int k = 0; k < 128; k += 4) {
        float4 a[4], b[5];
#pragma unroll
        for (int ri = 0; ri < 4; ri++) a[ri] = *(const float4*)(xp[ri] + k);
#pragma unroll
        for (int ci = 0; ci < 5; ci++) b[ci] = *(const float4*)(&WsT[SWZ(tx * 5 + ci, k)]);
#pragma unroll
        for (int ri = 0; ri < 4; ri++)
#pragma unroll
            for (int ci = 0; ci < 5; ci++) {
                acc[ri][ci] = fmaf(a[ri].x, b[ci].x, acc[ri][ci]);
                acc[ri][ci] = fmaf(a[ri].y, b[ci].y, acc[ri][ci]);
                acc[ri][ci] = fmaf(a[ri].z, b[ci].z, acc[ri][ci]);
                acc[ri][ci] = fmaf(a[ri].w, b[ci].w, acc[ri][ci]);
            }
    }

#pragma unroll
    for (int ri = 0; ri < 4; ri++) {
        int row = row0 + ty + 32 * ri;
        if (row >= n) continue;
        float di = dinv[row];
#pragma unroll
        for (int ci = 0; ci < 5; ci++)
            G[(size_t)row * 40 + tx * 5 + ci] = di * acc[ri][ci];
    }
}

// ---------- atomic-free aggregation (CSR), fused epilogue ----------

// 128 threads per node (2 nodes / 256-block); acc in register; relu epilogue.
__global__ __launch_bounds__(256) void aggregate128(const float* __restrict__ G,
                                                    const int* __restrict__ row_ptr,
                                                    const int* __restrict__ pos,
                                                    const int* __restrict__ csr_src,
                                                    const float* __restrict__ dinv,
                                                    const float* __restrict__ b,
                                                    float* __restrict__ Y, int n) {
    int node = blockIdx.x * 2 + (threadIdx.x >> 7);
    if (node >= n) return;
    int f = threadIdx.x & 127;
    float acc = G[(size_t)node * 128 + f];   // self-loop
    int p = row_ptr[node], p1 = pos[node];
    if (p < p1) {
        int s = csr_src[p];
        while (++p < p1) {
            int s2 = csr_src[p];             // prefetch next index
            acc += G[(size_t)s * 128 + f];
            s = s2;
        }
        acc += G[(size_t)s * 128 + f];
    }
    float v = fmaf(dinv[node], acc, b[f]);
    Y[(size_t)node * 128 + f] = v > 0.f ? v : 0.f;
}

// one 64-lane wave per node; 40 features; fused log_softmax -> d_out
__global__ __launch_bounds__(256) void aggregate40_lsm(const float* __restrict__ G,
                                                       const int* __restrict__ row_ptr,
                                                       const int* __restrict__ pos,
                                                       const int* __restrict__ csr_src,
                                                       const float* __restrict__ dinv,
                                                       const float* __restrict__ b,
                                                       float* __restrict__ Y, int n) {
    int node = blockIdx.x * 4 + (threadIdx.x >> 6);
    if (node >= n) return;
    int lane = threadIdx.x & 63;
    bool act = lane < 40;
    float acc = act ? G[(size_t)node * 40 + lane] : 0.f;
    int p = row_ptr[node], p1 = pos[node];
    for (; p < p1; ++p) {
        int s = csr_src[p];
        if (act) acc += G[(size_t)s * 40 + lane];
    }
    float v = act ? fmaf(dinv[node], acc, b[lane]) : -1e30f;
    float m = v;
#pragma unroll
    for (int off = 32; off > 0; off >>= 1) m = fmaxf(m, __shfl_xor(m, off, 64));
    float ex = act ? expf(v - m) : 0.f;
    float s_ = ex;
#pragma unroll
    for (int off = 32; off > 0; off >>= 1) s_ += __shfl_xor(s_, off, 64);
    float ls = logf(s_);
    if (act) Y[(size_t)node * 40 + lane] = v - m - ls;
}

// ---------- launch ----------

extern "C" void kernel_launch(void* const* d_in, const int* in_sizes, int n_in,
                              void* d_out, int out_size, void* d_ws, size_t ws_size,
                              hipStream_t stream) {
    const float* x  = (const float*)d_in[0];
    const int*   ei = (const int*)d_in[1];
    const float* W1 = (const float*)d_in[2];
    const float* b1 = (const float*)d_in[3];
    const float* W2 = (const float*)d_in[4];
    const float* b2 = (const float*)d_in[5];
    const float* W3 = (const float*)d_in[6];
    const float* b3 = (const float*)d_in[7];
    float* out = (float*)d_out;

    const int n = NN, e = NE;
    const int* srcI = ei;
    const int* dstI = ei + e;

    char* ws = (char*)d_ws;
    int*   hist    = (int*)ws;                               // n
    float* dinv    = (float*)(ws + 200704);                  // n
    int*   row_ptr = (int*)(ws + 401408);                    // n
    int*   pos     = (int*)(ws + 602112);                    // n
    int*   bsum    = (int*)(ws + 802816);                    // 256
    int*   boff    = (int*)(ws + 803840);                    // 256
    int*   csr_src = (int*)(ws + 804864);                    // E
    float* bufG    = (float*)(ws + 4005888);                 // n*128
    float* bufA    = (float*)(ws + 4005888 + 25600000);      // n*128

    int nb = (n + 255) / 256;  // 196 scan blocks

    // CSR + dinv
    zero_i<<<nb, 256, 0, stream>>>(hist, n);
    hist_acc<<<(e + 255) / 256, 256, 0, stream>>>(dstI, hist, e);
    dinv_k<<<nb, 256, 0, stream>>>(hist, dinv, n);
    scan1<<<nb, 256, 0, stream>>>(hist, row_ptr, bsum, n);
    scan2<<<1, 256, 0, stream>>>(bsum, boff, nb);
    scan3<<<nb, 256, 0, stream>>>(row_ptr, boff, pos, n);
    bucket<<<(e + 255) / 256, 256, 0, stream>>>(srcI, dstI, pos, csr_src, e);

    unsigned gg = (unsigned)((n + 127) / 128);
    unsigned ga128 = (unsigned)((n + 1) / 2);
    unsigned ga40 = (unsigned)((n + 3) / 4);

    // layer 1
    gemm128<<<gg, 256, 0, stream>>>(x, W1, dinv, bufG, n);
    aggregate128<<<ga128, 256, 0, stream>>>(bufG, row_ptr, pos, csr_src, dinv, b1, bufA, n);
    // layer 2
    gemm128<<<gg, 256, 0, stream>>>(bufA, W2, dinv, bufG, n);
    aggregate128<<<ga128, 256, 0, stream>>>(bufG, row_ptr, pos, csr_src, dinv, b2, bufA, n);
    // layer 3 (G40 reuses bufG)
    gemm40<<<gg, 256, 0, stream>>>(bufA, W3, dinv, bufG, n);
    aggregate40_lsm<<<ga40, 256, 0, stream>>>(bufG, row_ptr, pos, csr_src, dinv, b3, out, n);
}

// Round 5
// 383.129 us; speedup vs baseline: 9.2718x; 1.3944x over previous
//
#include <hip/hip_runtime.h>
#include <stdint.h>

#define NN 50000
#define NE 800000

#define SWZ(j, k) ((j) * 128 + ((k) ^ (((j) & 7) << 2)))

// ---- bf16 helpers (RNE) ----
__device__ inline unsigned short f2bf(float f) {
    union { float f; uint32_t u; } x; x.f = f;
    uint32_t u = x.u;
    return (unsigned short)((u + 0x7fffu + ((u >> 16) & 1u)) >> 16);
}
__device__ inline float bf2f(unsigned short h) {
    union { uint32_t u; float f; } c; c.u = ((uint32_t)h) << 16;
    return c.f;
}
__device__ inline float2 bfp2f2(uint32_t v) {
    union { uint32_t u; float f; } a, b;
    a.u = (v & 0xffffu) << 16;
    b.u = v & 0xffff0000u;
    return make_float2(a.f, b.f);
}

// ---------- CSR build ----------

__global__ void zero_i(int* p, int n) {
    int i = blockIdx.x * blockDim.x + threadIdx.x;
    if (i < n) p[i] = 0;
}

__global__ void hist_acc(const int* __restrict__ dst, int* hist, int e) {
    int i = blockIdx.x * blockDim.x + threadIdx.x;
    if (i < e) atomicAdd(hist + dst[i], 1);
}

__global__ void dinv_k(const int* __restrict__ hist, float* dinv, int n) {
    int i = blockIdx.x * blockDim.x + threadIdx.x;
    if (i < n) dinv[i] = rsqrtf(1.0f + (float)hist[i]);  // +1 self-loop
}

__global__ void scan1(const int* __restrict__ hist, int* row_ptr, int* bsum, int n) {
    __shared__ int s[256];
    int tid = threadIdx.x;
    int i = blockIdx.x * 256 + tid;
    int v = (i < n) ? hist[i] : 0;
    s[tid] = v;
    __syncthreads();
#pragma unroll
    for (int off = 1; off < 256; off <<= 1) {
        int y = (tid >= off) ? s[tid - off] : 0;
        __syncthreads();
        s[tid] += y;
        __syncthreads();
    }
    if (i < n) row_ptr[i] = s[tid] - v;
    if (tid == 255) bsum[blockIdx.x] = s[255];
}

__global__ void scan2(const int* __restrict__ bsum, int* boff, int nb) {
    __shared__ int s[256];
    int tid = threadIdx.x;
    int v = (tid < nb) ? bsum[tid] : 0;
    s[tid] = v;
    __syncthreads();
#pragma unroll
    for (int off = 1; off < 256; off <<= 1) {
        int y = (tid >= off) ? s[tid - off] : 0;
        __syncthreads();
        s[tid] += y;
        __syncthreads();
    }
    if (tid < nb) boff[tid] = s[tid] - v;
}

__global__ void scan3(int* row_ptr, const int* __restrict__ boff, int* pos, int n) {
    int i = blockIdx.x * blockDim.x + threadIdx.x;
    if (i < n) {
        int rp = row_ptr[i] + boff[i >> 8];
        row_ptr[i] = rp;
        pos[i] = rp;
    }
}

__global__ void bucket(const int* __restrict__ src, const int* __restrict__ dst,
                       int* pos, int* csr_src, int e) {
    int i = blockIdx.x * blockDim.x + threadIdx.x;
    if (i < e) {
        int p = atomicAdd(pos + dst[i], 1);
        csr_src[p] = src[i];
    }
}

// ---------- GEMMs: G written as bf16 ----------

__global__ __launch_bounds__(256) void gemm128(const float* __restrict__ X,
                                               const float* __restrict__ W,
                                               const float* __restrict__ dinv,
                                               unsigned short* __restrict__ G, int n) {
    __shared__ float WsT[128 * 128];
    int t = threadIdx.x;
    int row0 = blockIdx.x * 128;

    const float4* Wv = (const float4*)W;
#pragma unroll
    for (int i = 0; i < 16; i++) {
        int idx = t + i * 256;
        int k = idx >> 5;
        int j4 = (idx & 31) * 4;
        float4 v = Wv[idx];
        WsT[(j4 + 0) * 128 + (k ^ (((j4 + 0) & 7) << 2))] = v.x;
        WsT[(j4 + 1) * 128 + (k ^ (((j4 + 1) & 7) << 2))] = v.y;
        WsT[(j4 + 2) * 128 + (k ^ (((j4 + 2) & 7) << 2))] = v.z;
        WsT[(j4 + 3) * 128 + (k ^ (((j4 + 3) & 7) << 2))] = v.w;
    }
    __syncthreads();

    int tx = t & 15;
    int ty = t >> 4;

    const float* xp[8];
#pragma unroll
    for (int ri = 0; ri < 8; ri++) {
        int row = row0 + ty + 16 * ri;
        int rowc = row < n ? row : n - 1;
        xp[ri] = X + (size_t)rowc * 128;
    }

    float acc[8][8];
#pragma unroll
    for (int ri = 0; ri < 8; ri++)
#pragma unroll
        for (int ci = 0; ci < 8; ci++) acc[ri][ci] = 0.f;

#pragma unroll 2
    for (int k = 0; k < 128; k += 4) {
        float4 a[8], b[8];
#pragma unroll
        for (int ri = 0; ri < 8; ri++) a[ri] = *(const float4*)(xp[ri] + k);
#pragma unroll
        for (int ci = 0; ci < 8; ci++) b[ci] = *(const float4*)(&WsT[SWZ(tx + 16 * ci, k)]);
#pragma unroll
        for (int ri = 0; ri < 8; ri++)
#pragma unroll
            for (int ci = 0; ci < 8; ci++) {
                acc[ri][ci] = fmaf(a[ri].x, b[ci].x, acc[ri][ci]);
                acc[ri][ci] = fmaf(a[ri].y, b[ci].y, acc[ri][ci]);
                acc[ri][ci] = fmaf(a[ri].z, b[ci].z, acc[ri][ci]);
                acc[ri][ci] = fmaf(a[ri].w, b[ci].w, acc[ri][ci]);
            }
    }

#pragma unroll
    for (int ri = 0; ri < 8; ri++) {
        int row = row0 + ty + 16 * ri;
        if (row >= n) continue;
        float di = dinv[row];
#pragma unroll
        for (int ci = 0; ci < 8; ci++)
            G[(size_t)row * 128 + tx + 16 * ci] = f2bf(di * acc[ri][ci]);
    }
}

__global__ __launch_bounds__(256) void gemm40(const float* __restrict__ X,
                                              const float* __restrict__ W,
                                              const float* __restrict__ dinv,
                                              unsigned short* __restrict__ G, int n) {
    __shared__ float WsT[40 * 128];
    int t = threadIdx.x;
    int row0 = blockIdx.x * 128;

    const float4* Wv = (const float4*)W;
#pragma unroll
    for (int i = 0; i < 5; i++) {
        int idx = t + i * 256;
        int k = idx / 10;
        int j4 = (idx - k * 10) * 4;
        float4 v = Wv[idx];
        WsT[(j4 + 0) * 128 + (k ^ (((j4 + 0) & 7) << 2))] = v.x;
        WsT[(j4 + 1) * 128 + (k ^ (((j4 + 1) & 7) << 2))] = v.y;
        WsT[(j4 + 2) * 128 + (k ^ (((j4 + 2) & 7) << 2))] = v.z;
        WsT[(j4 + 3) * 128 + (k ^ (((j4 + 3) & 7) << 2))] = v.w;
    }
    __syncthreads();

    int tx = t & 7;
    int ty = t >> 3;

    const float* xp[4];
#pragma unroll
    for (int ri = 0; ri < 4; ri++) {
        int row = row0 + ty + 32 * ri;
        int rowc = row < n ? row : n - 1;
        xp[ri] = X + (size_t)rowc * 128;
    }

    float acc[4][5];
#pragma unroll
    for (int ri = 0; ri < 4; ri++)
#pragma unroll
        for (int ci = 0; ci < 5; ci++) acc[ri][ci] = 0.f;

#pragma unroll 2
    for (int k = 0; k < 128; k += 4) {
        float4 a[4], b[5];
#pragma unroll
        for (int ri = 0; ri < 4; ri++) a[ri] = *(const float4*)(xp[ri] + k);
#pragma unroll
        for (int ci = 0; ci < 5; ci++) b[ci] = *(const float4*)(&WsT[SWZ(tx * 5 + ci, k)]);
#pragma unroll
        for (int ri = 0; ri < 4; ri++)
#pragma unroll
            for (int ci = 0; ci < 5; ci++) {
                acc[ri][ci] = fmaf(a[ri].x, b[ci].x, acc[ri][ci]);
                acc[ri][ci] = fmaf(a[ri].y, b[ci].y, acc[ri][ci]);
                acc[ri][ci] = fmaf(a[ri].z, b[ci].z, acc[ri][ci]);
                acc[ri][ci] = fmaf(a[ri].w, b[ci].w, acc[ri][ci]);
            }
    }

#pragma unroll
    for (int ri = 0; ri < 4; ri++) {
        int row = row0 + ty + 32 * ri;
        if (row >= n) continue;
        float di = dinv[row];
#pragma unroll
        for (int ci = 0; ci < 5; ci++)
            G[(size_t)row * 40 + tx * 5 + ci] = f2bf(di * acc[ri][ci]);
    }
}

// ---------- aggregation: 1 wave/node, 2 bf16 features/lane, unroll x4 ----------

__global__ __launch_bounds__(256) void aggregate128(const unsigned short* __restrict__ G,
                                                    const int* __restrict__ row_ptr,
                                                    const int* __restrict__ pos,
                                                    const int* __restrict__ csr_src,
                                                    const float* __restrict__ dinv,
                                                    const float* __restrict__ b,
                                                    float* __restrict__ Y, int n) {
    int node = blockIdx.x * 4 + (threadIdx.x >> 6);
    if (node >= n) return;
    int l = threadIdx.x & 63;                 // feature pair: features 2l, 2l+1
    const uint32_t* Gr = (const uint32_t*)G;  // 64 uints per row

    float2 acc = bfp2f2(Gr[(size_t)node * 64 + l]);  // self-loop
    int p = row_ptr[node], p1 = pos[node];
    for (; p + 3 < p1; p += 4) {
        int s0 = csr_src[p], s1 = csr_src[p + 1], s2 = csr_src[p + 2], s3 = csr_src[p + 3];
        uint32_t v0 = Gr[(size_t)s0 * 64 + l];
        uint32_t v1 = Gr[(size_t)s1 * 64 + l];
        uint32_t v2 = Gr[(size_t)s2 * 64 + l];
        uint32_t v3 = Gr[(size_t)s3 * 64 + l];
        float2 f0 = bfp2f2(v0), f1 = bfp2f2(v1), f2 = bfp2f2(v2), f3 = bfp2f2(v3);
        acc.x += (f0.x + f1.x) + (f2.x + f3.x);
        acc.y += (f0.y + f1.y) + (f2.y + f3.y);
    }
    for (; p < p1; ++p) {
        float2 f = bfp2f2(Gr[(size_t)csr_src[p] * 64 + l]);
        acc.x += f.x; acc.y += f.y;
    }
    float di = dinv[node];
    float vx = fmaf(di, acc.x, b[2 * l]);
    float vy = fmaf(di, acc.y, b[2 * l + 1]);
    float2 o = make_float2(vx > 0.f ? vx : 0.f, vy > 0.f ? vy : 0.f);
    *(float2*)(Y + (size_t)node * 128 + 2 * l) = o;
}

// wave per node, 40 bf16 features, fused log_softmax -> out
__global__ __launch_bounds__(256) void aggregate40_lsm(const unsigned short* __restrict__ G,
                                                       const int* __restrict__ row_ptr,
                                                       const int* __restrict__ pos,
                                                       const int* __restrict__ csr_src,
                                                       const float* __restrict__ dinv,
                                                       const float* __restrict__ b,
                                                       float* __restrict__ Y, int n) {
    int node = blockIdx.x * 4 + (threadIdx.x >> 6);
    if (node >= n) return;
    int lane = threadIdx.x & 63;
    bool act = lane < 40;
    int lc = act ? lane : 0;
    float acc = act ? bf2f(G[(size_t)node * 40 + lane]) : 0.f;
    int p = row_ptr[node], p1 = pos[node];
    for (; p + 3 < p1; p += 4) {
        int s0 = csr_src[p], s1 = csr_src[p + 1], s2 = csr_src[p + 2], s3 = csr_src[p + 3];
        float f0 = bf2f(G[(size_t)s0 * 40 + lc]);
        float f1 = bf2f(G[(size_t)s1 * 40 + lc]);
        float f2 = bf2f(G[(size_t)s2 * 40 + lc]);
        float f3 = bf2f(G[(size_t)s3 * 40 + lc]);
        acc += (f0 + f1) + (f2 + f3);
    }
    for (; p < p1; ++p) acc += bf2f(G[(size_t)csr_src[p] * 40 + lc]);

    float v = act ? fmaf(dinv[node], acc, b[lane]) : -1e30f;
    float m = v;
#pragma unroll
    for (int off = 32; off > 0; off >>= 1) m = fmaxf(m, __shfl_xor(m, off, 64));
    float ex = act ? expf(v - m) : 0.f;
    float s_ = ex;
#pragma unroll
    for (int off = 32; off > 0; off >>= 1) s_ += __shfl_xor(s_, off, 64);
    float ls = logf(s_);
    if (act) Y[(size_t)node * 40 + lane] = v - m - ls;
}

// ---------- launch ----------

extern "C" void kernel_launch(void* const* d_in, const int* in_sizes, int n_in,
                              void* d_out, int out_size, void* d_ws, size_t ws_size,
                              hipStream_t stream) {
    const float* x  = (const float*)d_in[0];
    const int*   ei = (const int*)d_in[1];
    const float* W1 = (const float*)d_in[2];
    const float* b1 = (const float*)d_in[3];
    const float* W2 = (const float*)d_in[4];
    const float* b2 = (const float*)d_in[5];
    const float* W3 = (const float*)d_in[6];
    const float* b3 = (const float*)d_in[7];
    float* out = (float*)d_out;

    const int n = NN, e = NE;
    const int* srcI = ei;
    const int* dstI = ei + e;

    char* ws = (char*)d_ws;
    int*   hist    = (int*)ws;                               // n
    float* dinv    = (float*)(ws + 200704);                  // n
    int*   row_ptr = (int*)(ws + 401408);                    // n
    int*   pos     = (int*)(ws + 602112);                    // n
    int*   bsum    = (int*)(ws + 802816);                    // 256
    int*   boff    = (int*)(ws + 803840);                    // 256
    int*   csr_src = (int*)(ws + 804864);                    // E ints
    unsigned short* bufG = (unsigned short*)(ws + 4005888);  // n*128 bf16 (12.8 MB)
    float* bufA    = (float*)(ws + 4005888 + 12800000);      // n*128 fp32

    int nb = (n + 255) / 256;

    zero_i<<<nb, 256, 0, stream>>>(hist, n);
    hist_acc<<<(e + 255) / 256, 256, 0, stream>>>(dstI, hist, e);
    dinv_k<<<nb, 256, 0, stream>>>(hist, dinv, n);
    scan1<<<nb, 256, 0, stream>>>(hist, row_ptr, bsum, n);
    scan2<<<1, 256, 0, stream>>>(bsum, boff, nb);
    scan3<<<nb, 256, 0, stream>>>(row_ptr, boff, pos, n);
    bucket<<<(e + 255) / 256, 256, 0, stream>>>(srcI, dstI, pos, csr_src, e);

    unsigned gg = (unsigned)((n + 127) / 128);
    unsigned ga = (unsigned)((n + 3) / 4);

    // layer 1
    gemm128<<<gg, 256, 0, stream>>>(x, W1, dinv, bufG, n);
    aggregate128<<<ga, 256, 0, stream>>>(bufG, row_ptr, pos, csr_src, dinv, b1, bufA, n);
    // layer 2
    gemm128<<<gg, 256, 0, stream>>>(bufA, W2, dinv, bufG, n);
    aggregate128<<<ga, 256, 0, stream>>>(bufG, row_ptr, pos, csr_src, dinv, b2, bufA, n);
    // layer 3
    gemm40<<<gg, 256, 0, stream>>>(bufA, W3, dinv, bufG, n);
    aggregate40_lsm<<<ga, 256, 0, stream>>>(bufG, row_ptr, pos, csr_src, dinv, b3, out, n);
}

// Round 6
// 322.680 us; speedup vs baseline: 11.0087x; 1.1873x over previous
//
#include <hip/hip_runtime.h>
#include <stdint.h>

#define NN 50000
#define NE 800000

#define SWZ(j, k) ((j) * 128 + ((k) ^ (((j) & 7) << 2)))

// ---- bf16 helpers (RNE) ----
__device__ inline unsigned short f2bf(float f) {
    union { float f; uint32_t u; } x; x.f = f;
    uint32_t u = x.u;
    return (unsigned short)((u + 0x7fffu + ((u >> 16) & 1u)) >> 16);
}
__device__ inline uint32_t pack2bf(float lo, float hi) {
    return (uint32_t)f2bf(lo) | ((uint32_t)f2bf(hi) << 16);
}
__device__ inline float bf2f(unsigned short h) {
    union { uint32_t u; float f; } c; c.u = ((uint32_t)h) << 16;
    return c.f;
}
__device__ inline float2 bfp2f2(uint32_t v) {
    union { uint32_t u; float f; } a, b;
    a.u = (v & 0xffffu) << 16;
    b.u = v & 0xffff0000u;
    return make_float2(a.f, b.f);
}

#define FMA4(ACC, S, B)                  \
    ACC.x = fmaf(S, B.x, ACC.x);         \
    ACC.y = fmaf(S, B.y, ACC.y);         \
    ACC.z = fmaf(S, B.z, ACC.z);         \
    ACC.w = fmaf(S, B.w, ACC.w);

// ---------- CSR build ----------

__global__ void zero_i(int* p, int n) {
    int i = blockIdx.x * blockDim.x + threadIdx.x;
    if (i < n) p[i] = 0;
}

// histogram + per-edge rank (return value of the atomic IS the rank)
__global__ void hist_rank(const int* __restrict__ dst, int* hist, int* rank, int e) {
    int i = blockIdx.x * blockDim.x + threadIdx.x;
    if (i < e) rank[i] = atomicAdd(hist + dst[i], 1);
}

__global__ void dinv_k(const int* __restrict__ hist, float* dinv, int n) {
    int i = blockIdx.x * blockDim.x + threadIdx.x;
    if (i < n) dinv[i] = rsqrtf(1.0f + (float)hist[i]);  // +1 self-loop
}

__global__ void scan1(const int* __restrict__ hist, int* row_ptr, int* bsum, int n) {
    __shared__ int s[256];
    int tid = threadIdx.x;
    int i = blockIdx.x * 256 + tid;
    int v = (i < n) ? hist[i] : 0;
    s[tid] = v;
    __syncthreads();
#pragma unroll
    for (int off = 1; off < 256; off <<= 1) {
        int y = (tid >= off) ? s[tid - off] : 0;
        __syncthreads();
        s[tid] += y;
        __syncthreads();
    }
    if (i < n) row_ptr[i] = s[tid] - v;
    if (tid == 255) bsum[blockIdx.x] = s[255];
}

__global__ void scan2(const int* __restrict__ bsum, int* boff, int nb) {
    __shared__ int s[256];
    int tid = threadIdx.x;
    int v = (tid < nb) ? bsum[tid] : 0;
    s[tid] = v;
    __syncthreads();
#pragma unroll
    for (int off = 1; off < 256; off <<= 1) {
        int y = (tid >= off) ? s[tid - off] : 0;
        __syncthreads();
        s[tid] += y;
        __syncthreads();
    }
    if (tid < nb) boff[tid] = s[tid] - v;
}

__global__ void scan3(int* row_ptr, const int* __restrict__ boff, int n) {
    int i = blockIdx.x * blockDim.x + threadIdx.x;
    if (i < n) row_ptr[i] += boff[i >> 8];
}

// atomic-free bucket scatter: position = row_ptr[dst] + rank
__global__ void bucket(const int* __restrict__ src, const int* __restrict__ dst,
                       const int* __restrict__ row_ptr, const int* __restrict__ rank,
                       int* __restrict__ csr_src, int e) {
    int i = blockIdx.x * blockDim.x + threadIdx.x;
    if (i < e) csr_src[row_ptr[dst[i]] + rank[i]] = src[i];
}

// ---------- GEMMs: G written as bf16 ----------

// W staged row-major in LDS (coalesced copy, no transpose => no write conflicts).
// Register tile: 8 rows x 8 cols per thread, cols grouped {4tx..4tx+3, 64+4tx..+3}
// => ds_read_b128 at banks 4tx%32: 2-way aliasing (free).
__global__ __launch_bounds__(256) void gemm128(const float* __restrict__ X,
                                               const float* __restrict__ W,
                                               const float* __restrict__ dinv,
                                               unsigned short* __restrict__ G, int n) {
    __shared__ float Ws[128 * 128];  // 64 KB
    int t = threadIdx.x;
    int row0 = blockIdx.x * 128;

    const float4* Wv = (const float4*)W;
    float4* Wsv = (float4*)Ws;
#pragma unroll
    for (int i = 0; i < 16; i++) Wsv[t + i * 256] = Wv[t + i * 256];
    __syncthreads();

    int tx = t & 15;   // col groups: 4tx and 64+4tx
    int ty = t >> 4;   // rows = ty + 16*ri

    const float* xp[8];
#pragma unroll
    for (int ri = 0; ri < 8; ri++) {
        int row = row0 + ty + 16 * ri;
        int rowc = row < n ? row : n - 1;  // clamp; store is guarded
        xp[ri] = X + (size_t)rowc * 128;
    }

    float4 acc0[8], acc1[8];
#pragma unroll
    for (int ri = 0; ri < 8; ri++) {
        acc0[ri] = make_float4(0.f, 0.f, 0.f, 0.f);
        acc1[ri] = make_float4(0.f, 0.f, 0.f, 0.f);
    }

#pragma unroll 2
    for (int k = 0; k < 128; k += 4) {
        float4 a[8];
#pragma unroll
        for (int ri = 0; ri < 8; ri++) a[ri] = *(const float4*)(xp[ri] + k);
        float4 b0[4], b1[4];
#pragma unroll
        for (int c = 0; c < 4; c++) {
            b0[c] = *(const float4*)(&Ws[(k + c) * 128 + 4 * tx]);
            b1[c] = *(const float4*)(&Ws[(k + c) * 128 + 64 + 4 * tx]);
        }
#pragma unroll
        for (int ri = 0; ri < 8; ri++) {
            FMA4(acc0[ri], a[ri].x, b0[0]);
            FMA4(acc0[ri], a[ri].y, b0[1]);
            FMA4(acc0[ri], a[ri].z, b0[2]);
            FMA4(acc0[ri], a[ri].w, b0[3]);
            FMA4(acc1[ri], a[ri].x, b1[0]);
            FMA4(acc1[ri], a[ri].y, b1[1]);
            FMA4(acc1[ri], a[ri].z, b1[2]);
            FMA4(acc1[ri], a[ri].w, b1[3]);
        }
    }

#pragma unroll
    for (int ri = 0; ri < 8; ri++) {
        int row = row0 + ty + 16 * ri;
        if (row >= n) continue;
        float di = dinv[row];
        uint2 o0, o1;
        o0.x = pack2bf(di * acc0[ri].x, di * acc0[ri].y);
        o0.y = pack2bf(di * acc0[ri].z, di * acc0[ri].w);
        o1.x = pack2bf(di * acc1[ri].x, di * acc1[ri].y);
        o1.y = pack2bf(di * acc1[ri].z, di * acc1[ri].w);
        *(uint2*)(&G[(size_t)row * 128 + 4 * tx]) = o0;
        *(uint2*)(&G[(size_t)row * 128 + 64 + 4 * tx]) = o1;
    }
}

__global__ __launch_bounds__(256) void gemm40(const float* __restrict__ X,
                                              const float* __restrict__ W,
                                              const float* __restrict__ dinv,
                                              unsigned short* __restrict__ G, int n) {
    __shared__ float WsT[40 * 128];
    int t = threadIdx.x;
    int row0 = blockIdx.x * 128;

    const float4* Wv = (const float4*)W;
#pragma unroll
    for (int i = 0; i < 5; i++) {
        int idx = t + i * 256;
        int k = idx / 10;
        int j4 = (idx - k * 10) * 4;
        float4 v = Wv[idx];
        WsT[(j4 + 0) * 128 + (k ^ (((j4 + 0) & 7) << 2))] = v.x;
        WsT[(j4 + 1) * 128 + (k ^ (((j4 + 1) & 7) << 2))] = v.y;
        WsT[(j4 + 2) * 128 + (k ^ (((j4 + 2) & 7) << 2))] = v.z;
        WsT[(j4 + 3) * 128 + (k ^ (((j4 + 3) & 7) << 2))] = v.w;
    }
    __syncthreads();

    int tx = t & 7;
    int ty = t >> 3;

    const float* xp[4];
#pragma unroll
    for (int ri = 0; ri < 4; ri++) {
        int row = row0 + ty + 32 * ri;
        int rowc = row < n ? row : n - 1;
        xp[ri] = X + (size_t)rowc * 128;
    }

    float acc[4][5];
#pragma unroll
    for (int ri = 0; ri < 4; ri++)
#pragma unroll
        for (int ci = 0; ci < 5; ci++) acc[ri][ci] = 0.f;

#pragma unroll 2
    for (int k = 0; k < 128; k += 4) {
        float4 a[4], b[5];
#pragma unroll
        for (int ri = 0; ri < 4; ri++) a[ri] = *(const float4*)(xp[ri] + k);
#pragma unroll
        for (int ci = 0; ci < 5; ci++) b[ci] = *(const float4*)(&WsT[SWZ(tx * 5 + ci, k)]);
#pragma unroll
        for (int ri = 0; ri < 4; ri++)
#pragma unroll
            for (int ci = 0; ci < 5; ci++) {
                acc[ri][ci] = fmaf(a[ri].x, b[ci].x, acc[ri][ci]);
                acc[ri][ci] = fmaf(a[ri].y, b[ci].y, acc[ri][ci]);
                acc[ri][ci] = fmaf(a[ri].z, b[ci].z, acc[ri][ci]);
                acc[ri][ci] = fmaf(a[ri].w, b[ci].w, acc[ri][ci]);
            }
    }

#pragma unroll
    for (int ri = 0; ri < 4; ri++) {
        int row = row0 + ty + 32 * ri;
        if (row >= n) continue;
        float di = dinv[row];
#pragma unroll
        for (int ci = 0; ci < 5; ci++)
            G[(size_t)row * 40 + tx * 5 + ci] = f2bf(di * acc[ri][ci]);
    }
}

// ---------- aggregation: 1 wave/node, 2 bf16 features/lane, unroll x8 ----------

__global__ __launch_bounds__(256) void aggregate128(const unsigned short* __restrict__ G,
                                                    const int* __restrict__ row_ptr,
                                                    const int* __restrict__ hist,
                                                    const int* __restrict__ csr_src,
                                                    const float* __restrict__ dinv,
                                                    const float* __restrict__ b,
                                                    float* __restrict__ Y, int n) {
    int node = blockIdx.x * 4 + (threadIdx.x >> 6);
    if (node >= n) return;
    int l = threadIdx.x & 63;
    const uint32_t* Gr = (const uint32_t*)G;

    float2 acc = bfp2f2(Gr[(size_t)node * 64 + l]);  // self-loop
    int p = row_ptr[node], p1 = p + hist[node];
    for (; p + 7 < p1; p += 8) {
        int s0 = csr_src[p],     s1 = csr_src[p + 1], s2 = csr_src[p + 2], s3 = csr_src[p + 3];
        int s4 = csr_src[p + 4], s5 = csr_src[p + 5], s6 = csr_src[p + 6], s7 = csr_src[p + 7];
        uint32_t v0 = Gr[(size_t)s0 * 64 + l], v1 = Gr[(size_t)s1 * 64 + l];
        uint32_t v2 = Gr[(size_t)s2 * 64 + l], v3 = Gr[(size_t)s3 * 64 + l];
        uint32_t v4 = Gr[(size_t)s4 * 64 + l], v5 = Gr[(size_t)s5 * 64 + l];
        uint32_t v6 = Gr[(size_t)s6 * 64 + l], v7 = Gr[(size_t)s7 * 64 + l];
        float2 f0 = bfp2f2(v0), f1 = bfp2f2(v1), f2 = bfp2f2(v2), f3 = bfp2f2(v3);
        float2 f4 = bfp2f2(v4), f5 = bfp2f2(v5), f6 = bfp2f2(v6), f7 = bfp2f2(v7);
        acc.x += ((f0.x + f1.x) + (f2.x + f3.x)) + ((f4.x + f5.x) + (f6.x + f7.x));
        acc.y += ((f0.y + f1.y) + (f2.y + f3.y)) + ((f4.y + f5.y) + (f6.y + f7.y));
    }
    for (; p + 3 < p1; p += 4) {
        int s0 = csr_src[p], s1 = csr_src[p + 1], s2 = csr_src[p + 2], s3 = csr_src[p + 3];
        float2 f0 = bfp2f2(Gr[(size_t)s0 * 64 + l]), f1 = bfp2f2(Gr[(size_t)s1 * 64 + l]);
        float2 f2 = bfp2f2(Gr[(size_t)s2 * 64 + l]), f3 = bfp2f2(Gr[(size_t)s3 * 64 + l]);
        acc.x += (f0.x + f1.x) + (f2.x + f3.x);
        acc.y += (f0.y + f1.y) + (f2.y + f3.y);
    }
    for (; p < p1; ++p) {
        float2 f = bfp2f2(Gr[(size_t)csr_src[p] * 64 + l]);
        acc.x += f.x; acc.y += f.y;
    }
    float di = dinv[node];
    float vx = fmaf(di, acc.x, b[2 * l]);
    float vy = fmaf(di, acc.y, b[2 * l + 1]);
    float2 o = make_float2(vx > 0.f ? vx : 0.f, vy > 0.f ? vy : 0.f);
    *(float2*)(Y + (size_t)node * 128 + 2 * l) = o;
}

__global__ __launch_bounds__(256) void aggregate40_lsm(const unsigned short* __restrict__ G,
                                                       const int* __restrict__ row_ptr,
                                                       const int* __restrict__ hist,
                                                       const int* __restrict__ csr_src,
                                                       const float* __restrict__ dinv,
                                                       const float* __restrict__ b,
                                                       float* __restrict__ Y, int n) {
    int node = blockIdx.x * 4 + (threadIdx.x >> 6);
    if (node >= n) return;
    int lane = threadIdx.x & 63;
    bool act = lane < 40;
    int lc = act ? lane : 0;
    float acc = act ? bf2f(G[(size_t)node * 40 + lane]) : 0.f;
    int p = row_ptr[node], p1 = p + hist[node];
    for (; p + 3 < p1; p += 4) {
        int s0 = csr_src[p], s1 = csr_src[p + 1], s2 = csr_src[p + 2], s3 = csr_src[p + 3];
        float f0 = bf2f(G[(size_t)s0 * 40 + lc]);
        float f1 = bf2f(G[(size_t)s1 * 40 + lc]);
        float f2 = bf2f(G[(size_t)s2 * 40 + lc]);
        float f3 = bf2f(G[(size_t)s3 * 40 + lc]);
        acc += (f0 + f1) + (f2 + f3);
    }
    for (; p < p1; ++p) acc += bf2f(G[(size_t)csr_src[p] * 40 + lc]);

    float v = act ? fmaf(dinv[node], acc, b[lane]) : -1e30f;
    float m = v;
#pragma unroll
    for (int off = 32; off > 0; off >>= 1) m = fmaxf(m, __shfl_xor(m, off, 64));
    float ex = act ? expf(v - m) : 0.f;
    float s_ = ex;
#pragma unroll
    for (int off = 32; off > 0; off >>= 1) s_ += __shfl_xor(s_, off, 64);
    float ls = logf(s_);
    if (act) Y[(size_t)node * 40 + lane] = v - m - ls;
}

// ---------- launch ----------

extern "C" void kernel_launch(void* const* d_in, const int* in_sizes, int n_in,
                              void* d_out, int out_size, void* d_ws, size_t ws_size,
                              hipStream_t stream) {
    const float* x  = (const float*)d_in[0];
    const int*   ei = (const int*)d_in[1];
    const float* W1 = (const float*)d_in[2];
    const float* b1 = (const float*)d_in[3];
    const float* W2 = (const float*)d_in[4];
    const float* b2 = (const float*)d_in[5];
    const float* W3 = (const float*)d_in[6];
    const float* b3 = (const float*)d_in[7];
    float* out = (float*)d_out;

    const int n = NN, e = NE;
    const int* srcI = ei;
    const int* dstI = ei + e;

    char* ws = (char*)d_ws;
    int*   hist    = (int*)ws;                               // n          @ 0
    float* dinv    = (float*)(ws + 200704);                  // n
    int*   row_ptr = (int*)(ws + 401408);                    // n
    int*   bsum    = (int*)(ws + 602112);                    // 256
    int*   boff    = (int*)(ws + 603136);                    // 256
    int*   rank    = (int*)(ws + 604160);                    // E
    int*   csr_src = (int*)(ws + 3804160);                   // E
    unsigned short* bufG = (unsigned short*)(ws + 7004160);  // n*128 bf16
    float* bufA    = (float*)(ws + 7004160 + 12800000);      // n*128 fp32

    int nb = (n + 255) / 256;

    zero_i<<<nb, 256, 0, stream>>>(hist, n);
    hist_rank<<<(e + 255) / 256, 256, 0, stream>>>(dstI, hist, rank, e);
    dinv_k<<<nb, 256, 0, stream>>>(hist, dinv, n);
    scan1<<<nb, 256, 0, stream>>>(hist, row_ptr, bsum, n);
    scan2<<<1, 256, 0, stream>>>(bsum, boff, nb);
    scan3<<<nb, 256, 0, stream>>>(row_ptr, boff, n);
    bucket<<<(e + 255) / 256, 256, 0, stream>>>(srcI, dstI, row_ptr, rank, csr_src, e);

    unsigned gg = (unsigned)((n + 127) / 128);
    unsigned ga = (unsigned)((n + 3) / 4);

    // layer 1
    gemm128<<<gg, 256, 0, stream>>>(x, W1, dinv, bufG, n);
    aggregate128<<<ga, 256, 0, stream>>>(bufG, row_ptr, hist, csr_src, dinv, b1, bufA, n);
    // layer 2
    gemm128<<<gg, 256, 0, stream>>>(bufA, W2, dinv, bufG, n);
    aggregate128<<<ga, 256, 0, stream>>>(bufG, row_ptr, hist, csr_src, dinv, b2, bufA, n);
    // layer 3
    gemm40<<<gg, 256, 0, stream>>>(bufA, W3, dinv, bufG, n);
    aggregate40_lsm<<<ga, 256, 0, stream>>>(bufG, row_ptr, hist, csr_src, dinv, b3, out, n);
}